// Round 1
// baseline (103.239 us; speedup 1.0000x reference)
//
#include <hip/hip_runtime.h>

// Problem constants
#define IMGX   144
#define PATCH  4
#define NPS    36      // patches per side
#define NTOKB  1296    // tokens per batch
#define ED     16      // embedding dim
#define BATCH  4
#define NTOK   5184    // total tokens
#define CH     64      // tokens per chunk
#define NCHUNK 21      // ceil(1296/64): 20 full chunks + 16-token tail
#define LSTR   20      // LDS dwords per token: stride 20 sweeps all 32 banks (proven conflict-free)
#define RPW    4       // query rows per wave
#define BPB    324     // blocks per batch = 1296/RPW
#define PREP_BLOCKS 21

// Module-scope scratch (load-time allocated; capture-safe, no d_ws).
__device__ float g_partial[PREP_BLOCKS];  // per-block input maxima
__device__ float g_norms[NTOK];           // per-token squared norms (raw x)

// Kernel 1: per-token squared norms + per-block max (unchanged; proven).
__global__ __launch_bounds__(256) void prep_kernel(const float* __restrict__ x) {
    __shared__ float wmax[4];
    const int tid = threadIdx.x;
    const int t = blockIdx.x * 256 + tid;
    float m = 0.0f;
    if (t < NTOK) {
        const float4* p = (const float4*)(x + t * ED);
        float v[16];
        float4* v4 = (float4*)v;
        v4[0] = p[0]; v4[1] = p[1]; v4[2] = p[2]; v4[3] = p[3];
        float ns = 0.0f;
#pragma unroll
        for (int k = 0; k < 16; k++) {
            ns = fmaf(v[k], v[k], ns);
            m = fmaxf(m, v[k]);  // x >= 0 (uniform[0,1)), 0-init safe
        }
        g_norms[t] = ns;
    }
#pragma unroll
    for (int s = 32; s; s >>= 1) m = fmaxf(m, __shfl_xor(m, s));
    if ((tid & 63) == 0) wmax[tid >> 6] = m;
    __syncthreads();
    if (tid == 0) {
        g_partial[blockIdx.x] = fmaxf(fmaxf(wmax[0], wmax[1]), fmaxf(wmax[2], wmax[3]));
    }
}

// Kernel 2: fused attention + merging. ONE wave per block, FOUR query rows per
// wave. Each lane owns token j = j0+lane of the staged chunk: reads its 64B
// from LDS once and reuses it for 4 dots + 4 accumulations (LDS traffic /4 vs
// the 1-row-per-wave version). Single-wave blocks make __syncthreads a cheap
// waitcnt and give 1296 blocks -> 5.06/CU load balance.
//
// Math: softmax logit l_ij = s*(2*dot - n_j) - s*n_i, s = 1/(16*xmax^2).
// Row-constant -s*n_i cancels in softmax, so use p = exp2(c2*dot - cn*n_j)
// with c2 = 2s*log2e folded into the pre-scaled query registers and
// cn = s*log2e. Exponent <= 2*log2e -> p <= e^2, denom >= e^{s*n_i - 1} > 0.3:
// no overflow, no online softmax, no max subtraction.
__global__ __launch_bounds__(64) void attn_kernel(const float* __restrict__ x,
                                                  float* __restrict__ out) {
    __shared__ float lds[2][CH * LSTR];  // double-buffered chunk staging

    const int lane = threadIdx.x;        // 0..63
    const int wid  = blockIdx.x;         // 0..1295
    const int b    = wid / BPB;
    const int i0   = (wid - b * BPB) * RPW;  // first of 4 query rows

    const float* __restrict__ xb    = x + b * (NTOKB * ED);
    const float* __restrict__ norms = g_norms + b * NTOKB;

    // Global max from the 21 prep partials (full 64-lane butterfly).
    float pm = (lane < PREP_BLOCKS) ? g_partial[lane] : 0.0f;
#pragma unroll
    for (int sh = 32; sh; sh >>= 1) pm = fmaxf(pm, __shfl_xor(pm, sh));
    const float xmax = pm;
    const float s  = 1.0f / (16.0f * xmax * xmax);
    const float c2 = 2.0f * s * 1.4426950408889634f;  // 2s*log2(e) -> queries
    const float cn = s * 1.4426950408889634f;         // s*log2(e)  -> n_j

    // 4 query rows, pre-scaled by c2 so dot directly yields the log2 exponent.
    float ti[RPW][16];
#pragma unroll
    for (int r = 0; r < RPW; r++) {
        const float4* p = (const float4*)(xb + (i0 + r) * ED);
#pragma unroll
        for (int q = 0; q < 4; q++) {
            const float4 a = p[q];
            ti[r][q * 4 + 0] = a.x * c2;
            ti[r][q * 4 + 1] = a.y * c2;
            ti[r][q * 4 + 2] = a.z * c2;
            ti[r][q * 4 + 3] = a.w * c2;
        }
    }

    float o[RPW][16];
#pragma unroll
    for (int r = 0; r < RPW; r++)
#pragma unroll
        for (int k = 0; k < 16; k++) o[r][k] = 0.0f;
    float den0 = 0.0f, den1 = 0.0f, den2 = 0.0f, den3 = 0.0f;

    // Staging map: thread t loads quarter (t&3) of tokens {16q + (t>>2)}.
    // Global side: each of the 4 loads covers a dense 1KB slab (coalesced).
    // LDS side: identical address pattern to the proven stride-20 layout.
    const int stok = lane >> 2;  // 0..15
    const int sq   = lane & 3;

    float4 st[4];
    float njnext;
    {  // prefetch + stage chunk 0
#pragma unroll
        for (int q = 0; q < 4; q++)
            st[q] = ((const float4*)(xb + (q * 16 + stok) * ED))[sq];
        njnext = norms[lane];
    }
#pragma unroll
    for (int q = 0; q < 4; q++)
        *((float4*)&lds[0][(q * 16 + stok) * LSTR + sq * 4]) = st[q];

    for (int c = 0; c < NCHUNK; c++) {
        const int j0 = c * CH;
        const float njcur = njnext;

        // Issue next chunk's global loads NOW; their latency hides under the
        // ~140-instruction compute phase below. ds_write happens after.
        if (c + 1 < NCHUNK) {
            const int jb = j0 + CH;
#pragma unroll
            for (int q = 0; q < 4; q++) {
                const int jt = jb + q * 16 + stok;
                float4 z; z.x = z.y = z.z = z.w = 0.0f;
                st[q] = (jt < NTOKB) ? ((const float4*)(xb + jt * ED))[sq] : z;
            }
            const int jn = jb + lane;
            njnext = (jn < NTOKB) ? norms[jn] : 0.0f;
        }

        __syncthreads();  // single-wave: cheap lgkmcnt drain; lds[c&1] ready

        const int jj = j0 + lane;
        if (jj < NTOKB) {
            float tj[16];
            {
                const float4* lp = (const float4*)&lds[c & 1][lane * LSTR];
                ((float4*)tj)[0] = lp[0];
                ((float4*)tj)[1] = lp[1];
                ((float4*)tj)[2] = lp[2];
                ((float4*)tj)[3] = lp[3];
            }
            float d0 = 0.0f, d1 = 0.0f, d2 = 0.0f, d3 = 0.0f;
#pragma unroll
            for (int k = 0; k < 16; k++) {
                const float t = tj[k];
                d0 = fmaf(ti[0][k], t, d0);
                d1 = fmaf(ti[1][k], t, d1);
                d2 = fmaf(ti[2][k], t, d2);
                d3 = fmaf(ti[3][k], t, d3);
            }
            const float cc = cn * njcur;
            const float e0 = exp2f(d0 - cc);
            const float e1 = exp2f(d1 - cc);
            const float e2 = exp2f(d2 - cc);
            const float e3 = exp2f(d3 - cc);
            den0 += e0; den1 += e1; den2 += e2; den3 += e3;
#pragma unroll
            for (int k = 0; k < 16; k++) {
                const float t = tj[k];
                o[0][k] = fmaf(e0, t, o[0][k]);
                o[1][k] = fmaf(e1, t, o[1][k]);
                o[2][k] = fmaf(e2, t, o[2][k]);
                o[3][k] = fmaf(e3, t, o[3][k]);
            }
        }

        // Stage next chunk into the other buffer (vmcnt wait lands here, after
        // compute). Next iteration's __syncthreads makes it visible.
        if (c + 1 < NCHUNK) {
#pragma unroll
            for (int q = 0; q < 4; q++)
                *((float4*)&lds[(c + 1) & 1][(q * 16 + stok) * LSTR + sq * 4]) = st[q];
        }
    }

    // Denominators: plain 64-lane butterfly (4 values).
#pragma unroll
    for (int sh = 32; sh; sh >>= 1) {
        den0 += __shfl_xor(den0, sh);
        den1 += __shfl_xor(den1, sh);
        den2 += __shfl_xor(den2, sh);
        den3 += __shfl_xor(den3, sh);
    }

    // Output: split-butterfly over the 64 flattened partials (idx = r*16+d).
    // At mask m, each lane keeps the half whose idx-bit matches its lane-bit;
    // after all 6 steps lane L's V(0) holds the full sum of idx = L.
    // 63 shuffles total vs ~400 for four full 16-value butterflies.
#define V(n) o[(n) >> 4][(n) & 15]
#pragma unroll
    for (int m = 32; m; m >>= 1) {
        const bool hi = (lane & m) != 0;
#pragma unroll
        for (int k = 0; k < m; k++) {
            const float give = hi ? V(k) : V(k + m);
            const float got  = __shfl_xor(give, m);
            V(k) = (hi ? V(k + m) : V(k)) + got;
        }
    }

    // lane -> (row r = lane>>4, elem d = lane&15); select this row's denom.
    const float dl = (lane & 16) ? den1 : den0;
    const float dh = (lane & 16) ? den3 : den2;
    const float dd = (lane & 32) ? dh : dl;
    const float val = V(0) / dd;

    // Merging permutation: row i -> patch (by,bx); d=(ky,kx) -> pixel.
    const int r  = lane >> 4;
    const int d  = lane & 15;
    const int i  = i0 + r;
    const int by = i / NPS;
    const int bx = i - by * NPS;
    out[b * (IMGX * IMGX) + (by * PATCH + (d >> 2)) * IMGX + bx * PATCH + (d & 3)] = val;
#undef V
}

extern "C" void kernel_launch(void* const* d_in, const int* in_sizes, int n_in,
                              void* d_out, int out_size, void* d_ws, size_t ws_size,
                              hipStream_t stream) {
    const float* x = (const float*)d_in[0];  // f32 (4,1,144,144)
    float* out = (float*)d_out;              // f32 (4,1,144,144)
    (void)d_ws; (void)ws_size;

    hipLaunchKernelGGL(prep_kernel, dim3(PREP_BLOCKS), dim3(256), 0, stream, x);
    hipLaunchKernelGGL(attn_kernel, dim3(NTOKB), dim3(64), 0, stream, x, out);
}

// Round 2
// 70.929 us; speedup vs baseline: 1.4555x; 1.4555x over previous
//
#include <hip/hip_runtime.h>

// Problem constants
#define IMGX   144
#define PATCH  4
#define NPS    36      // patches per side
#define NTOKB  1296    // tokens per batch
#define ED     16      // embedding dim
#define NTOK   5184    // total tokens
#define RPW    4       // query rows per block (shared by all 4 waves)
#define BPB    324     // blocks per batch = 1296/RPW
#define SPAN   324     // j-tokens per wave = NTOKB/4
#define SITER  6       // ceil(SPAN/64): 5 full iterations + 4-lane tail
#define PREP_BLOCKS 21

// Module-scope scratch (load-time allocated; capture-safe, no d_ws).
__device__ float g_partial[PREP_BLOCKS];  // per-block input maxima
__device__ float g_norms[NTOK];           // per-token squared norms (raw x)

// Kernel 1: per-token squared norms + per-block max (unchanged; proven).
__global__ __launch_bounds__(256) void prep_kernel(const float* __restrict__ x) {
    __shared__ float wmax[4];
    const int tid = threadIdx.x;
    const int t = blockIdx.x * 256 + tid;
    float m = 0.0f;
    if (t < NTOK) {
        const float4* p = (const float4*)(x + t * ED);
        float v[16];
        float4* v4 = (float4*)v;
        v4[0] = p[0]; v4[1] = p[1]; v4[2] = p[2]; v4[3] = p[3];
        float ns = 0.0f;
#pragma unroll
        for (int k = 0; k < 16; k++) {
            ns = fmaf(v[k], v[k], ns);
            m = fmaxf(m, v[k]);  // x >= 0 (uniform[0,1)), 0-init safe
        }
        g_norms[t] = ns;
    }
#pragma unroll
    for (int s = 32; s; s >>= 1) m = fmaxf(m, __shfl_xor(m, s));
    if ((tid & 63) == 0) wmax[tid >> 6] = m;
    __syncthreads();
    if (tid == 0) {
        g_partial[blockIdx.x] = fmaxf(fmaxf(wmax[0], wmax[1]), fmaxf(wmax[2], wmax[3]));
    }
}

// Kernel 2: fused attention + merging.
// 1296 blocks x 256 threads (round-0 occupancy: 5184 waves, ~20/CU).
// The 4 waves of a block SHARE the block's 4 query rows but SPLIT the j-space
// into 4 spans of 324 tokens -> each lane owns token j and reuses its 64B for
// 4 dots + 4 accumulations (round-1's /4 traffic win), with NO barriers and NO
// LDS in the main loop. j-tokens are read directly from global (L2-resident,
// 332KB total working set) with a one-iteration register prefetch; the ~280cyc
// compute phase covers the ~200cyc L2 latency. One __syncthreads at the end
// for a tiny cross-wave LDS reduction.
//
// Math: softmax logit l_ij = s*(2*dot - n_j) - s*n_i, s = 1/(16*xmax^2).
// Row-constant -s*n_i cancels in softmax -> p = exp2(c2*dot - cn*n_j) with
// c2 = 2s*log2e folded into the query registers, cn = s*log2e. Exponent in
// [-log2e, 2*log2e] -> p <= e^2: no overflow, no online softmax.
__global__ __launch_bounds__(256, 2) void attn_kernel(const float* __restrict__ x,
                                                      float* __restrict__ out) {
    __shared__ float redo[4][64];  // per-wave output partials (idx = r*16+d)
    __shared__ float redd[4][4];   // per-wave denominator partials (per row)

    const int tid  = threadIdx.x;
    const int lane = tid & 63;
    const int w    = tid >> 6;            // wave id = j-span id
    const int blk  = blockIdx.x;          // 0..1295
    const int b    = blk / BPB;
    const int i0   = (blk - b * BPB) * RPW;

    const float* __restrict__ xb    = x + b * (NTOKB * ED);
    const float* __restrict__ norms = g_norms + b * NTOKB;

    // Global max from the 21 prep partials (full 64-lane butterfly).
    float pm = (lane < PREP_BLOCKS) ? g_partial[lane] : 0.0f;
#pragma unroll
    for (int sh = 32; sh; sh >>= 1) pm = fmaxf(pm, __shfl_xor(pm, sh));
    const float xmax = pm;
    const float s  = 1.0f / (16.0f * xmax * xmax);
    const float c2 = 2.0f * s * 1.4426950408889634f;  // 2s*log2(e) -> queries
    const float cn = s * 1.4426950408889634f;         // s*log2(e)  -> n_j

    // 4 query rows, pre-scaled by c2 so dot directly yields the log2 exponent.
    float ti[RPW][16];
#pragma unroll
    for (int r = 0; r < RPW; r++) {
        const float4* p = (const float4*)(xb + (i0 + r) * ED);
#pragma unroll
        for (int q = 0; q < 4; q++) {
            const float4 a = p[q];
            ti[r][q * 4 + 0] = a.x * c2;
            ti[r][q * 4 + 1] = a.y * c2;
            ti[r][q * 4 + 2] = a.z * c2;
            ti[r][q * 4 + 3] = a.w * c2;
        }
    }

    float o[RPW][16];
#pragma unroll
    for (int r = 0; r < RPW; r++)
#pragma unroll
        for (int k = 0; k < 16; k++) o[r][k] = 0.0f;
    float den0 = 0.0f, den1 = 0.0f, den2 = 0.0f, den3 = 0.0f;

    const int jbase = w * SPAN;

    // Prefetch iteration 0 (all 64 lanes valid: 64 <= SPAN).
    float4 cur[4];
    float  njc;
    {
        const float4* p = (const float4*)(xb + (jbase + lane) * ED);
        cur[0] = p[0]; cur[1] = p[1]; cur[2] = p[2]; cur[3] = p[3];
        njc = norms[jbase + lane];
    }

#pragma unroll
    for (int c = 0; c < SITER; c++) {
        // Issue next iteration's loads first; vmcnt wait lands at the cur=nxt
        // copy after ~280 cycles of compute (covers L2 latency).
        float4 nxt[4];
        float  njn = 0.0f;
        if (c + 1 < SITER) {
            const int jn  = jbase + (c + 1) * 64 + lane;
            const int jcl = (jn - jbase < SPAN) ? jn : jbase;  // clamp tail addr
            const float4* p = (const float4*)(xb + jcl * ED);
            nxt[0] = p[0]; nxt[1] = p[1]; nxt[2] = p[2]; nxt[3] = p[3];
            njn = norms[jcl];
        }

        const bool valid = (c * 64 + lane) < SPAN;  // only tail iter masks
        const float* tj = (const float*)cur;

        float d0 = 0.0f, d1 = 0.0f, d2 = 0.0f, d3 = 0.0f;
#pragma unroll
        for (int k = 0; k < 16; k++) {
            const float t = tj[k];
            d0 = fmaf(ti[0][k], t, d0);
            d1 = fmaf(ti[1][k], t, d1);
            d2 = fmaf(ti[2][k], t, d2);
            d3 = fmaf(ti[3][k], t, d3);
        }
        const float cc = cn * njc;
        float e0 = __builtin_amdgcn_exp2f(d0 - cc);
        float e1 = __builtin_amdgcn_exp2f(d1 - cc);
        float e2 = __builtin_amdgcn_exp2f(d2 - cc);
        float e3 = __builtin_amdgcn_exp2f(d3 - cc);
        e0 = valid ? e0 : 0.0f;
        e1 = valid ? e1 : 0.0f;
        e2 = valid ? e2 : 0.0f;
        e3 = valid ? e3 : 0.0f;
        den0 += e0; den1 += e1; den2 += e2; den3 += e3;
#pragma unroll
        for (int k = 0; k < 16; k++) {
            const float t = tj[k];
            o[0][k] = fmaf(e0, t, o[0][k]);
            o[1][k] = fmaf(e1, t, o[1][k]);
            o[2][k] = fmaf(e2, t, o[2][k]);
            o[3][k] = fmaf(e3, t, o[3][k]);
        }

        if (c + 1 < SITER) {
            cur[0] = nxt[0]; cur[1] = nxt[1]; cur[2] = nxt[2]; cur[3] = nxt[3];
            njc = njn;
        }
    }

    // Denominators: plain 64-lane butterfly (4 values) -> every lane has sums.
#pragma unroll
    for (int sh = 32; sh; sh >>= 1) {
        den0 += __shfl_xor(den0, sh);
        den1 += __shfl_xor(den1, sh);
        den2 += __shfl_xor(den2, sh);
        den3 += __shfl_xor(den3, sh);
    }

    // Output partials: split-butterfly over the 64 flattened values
    // (idx = r*16+d). After 6 steps lane L's V(0) holds this wave's full
    // partial for idx = L. (Identical to round-1's verified reduction.)
#define V(n) o[(n) >> 4][(n) & 15]
#pragma unroll
    for (int m = 32; m; m >>= 1) {
        const bool hi = (lane & m) != 0;
#pragma unroll
        for (int k = 0; k < m; k++) {
            const float give = hi ? V(k) : V(k + m);
            const float got  = __shfl_xor(give, m);
            V(k) = (hi ? V(k + m) : V(k)) + got;
        }
    }

    redo[w][lane] = V(0);
    if (lane == 0) {
        redd[w][0] = den0; redd[w][1] = den1; redd[w][2] = den2; redd[w][3] = den3;
    }
    __syncthreads();

    if (w == 0) {
        const float v = redo[0][lane] + redo[1][lane] + redo[2][lane] + redo[3][lane];
        const int r = lane >> 4;
        const int d = lane & 15;
        const float den = redd[0][r] + redd[1][r] + redd[2][r] + redd[3][r];
        const float val = v / den;

        // Merging permutation: row i -> patch (by,bx); d=(ky,kx) -> pixel.
        const int i  = i0 + r;
        const int by = i / NPS;
        const int bx = i - by * NPS;
        out[b * (IMGX * IMGX) + (by * PATCH + (d >> 2)) * IMGX + bx * PATCH + (d & 3)] = val;
    }
#undef V
}

extern "C" void kernel_launch(void* const* d_in, const int* in_sizes, int n_in,
                              void* d_out, int out_size, void* d_ws, size_t ws_size,
                              hipStream_t stream) {
    const float* x = (const float*)d_in[0];  // f32 (4,1,144,144)
    float* out = (float*)d_out;              // f32 (4,1,144,144)
    (void)d_ws; (void)ws_size;

    hipLaunchKernelGGL(prep_kernel, dim3(PREP_BLOCKS), dim3(256), 0, stream, x);
    hipLaunchKernelGGL(attn_kernel, dim3(NTOKB), dim3(256), 0, stream, x, out);
}